// Round 6
// baseline (159.953 us; speedup 1.0000x reference)
//
#include <hip/hip_runtime.h>

// Problem constants
#define BATCH   8
#define NNODES  16384
#define KNBR    16
#define LATENT  128
#define DOUT    32
#define NROWS   (BATCH * NNODES)          // 131072 rows

typedef __attribute__((ext_vector_type(8))) short short8;   // 8 bf16 (4 VGPRs)
typedef __attribute__((ext_vector_type(4))) float floatx4;  // native float4
typedef __attribute__((ext_vector_type(4))) unsigned uintx4;

__device__ __forceinline__ unsigned short f2bf(float f) {   // fp32 -> bf16 RNE
    unsigned u = __float_as_uint(f);
    u += 0x7fff + ((u >> 16) & 1);
    return (unsigned short)(u >> 16);
}

__device__ __forceinline__ short8 pack8(const floatx4 a, const floatx4 b) {
    short8 r;
    r[0] = (short)f2bf(a.x); r[1] = (short)f2bf(a.y);
    r[2] = (short)f2bf(a.z); r[3] = (short)f2bf(a.w);
    r[4] = (short)f2bf(b.x); r[5] = (short)f2bf(b.y);
    r[6] = (short)f2bf(b.z); r[7] = (short)f2bf(b.w);
    return r;
}

__device__ __forceinline__ float dot2bf(unsigned a, unsigned b) {
    float alo = __uint_as_float(a << 16);
    float ahi = __uint_as_float(a & 0xffff0000u);
    float blo = __uint_as_float(b << 16);
    float bhi = __uint_as_float(b & 0xffff0000u);
    return alo * blo + ahi * bhi;
}

// ---------------------------------------------------------------------------
// Kernel 1: bf16 MFMA projection, LDS-free.
// C[256 x 64] per block = feats[256x128] * [kw|qw]^T.  4 waves, wave w owns
// rows [w*64, w*64+64) as a 4x4 grid of 16x16 tiles; K in 4 steps of 32.
// A has ZERO cross-wave reuse -> fragments load straight from global with
// nontemporal hint (per wave-instr: 16 rows x 64B contiguous = full lines).
// B (32KB) is L1/L2-resident across blocks -> direct global fragment loads.
// No __shared__, no __syncthreads.
// ---------------------------------------------------------------------------
__global__ __launch_bounds__(256) void proj_kernel(
    const float* __restrict__ feats,
    const float* __restrict__ kw, const float* __restrict__ kb,
    const float* __restrict__ qw, const float* __restrict__ qb,
    unsigned short* __restrict__ tkb, unsigned short* __restrict__ tqb)
{
    const int tid  = threadIdx.x;
    const int lane = tid & 63;
    const int w    = tid >> 6;                 // wave 0..3
    const long long blk_row = (long long)blockIdx.x * 256;
    const int m = lane & 15;                   // MFMA row (A) / col (B,C)
    const int q = lane >> 4;                   // quad: k-offset q*8

    floatx4 acc[4][4];
#pragma unroll
    for (int rt = 0; rt < 4; ++rt)
#pragma unroll
        for (int ct = 0; ct < 4; ++ct) acc[rt][ct] = (floatx4){0.f, 0.f, 0.f, 0.f};

    const floatx4* f4  = (const floatx4*)feats;  // feature row = 32 f4
    const floatx4* kw4 = (const floatx4*)kw;     // 32 rows x 32 f4
    const floatx4* qw4 = (const floatx4*)qw;

#pragma unroll
    for (int ks = 0; ks < 4; ++ks) {
        const int kf4 = ks * 8 + q * 2;        // first of 2 f4 cols this lane needs

        // B fragments: rows ct*16+m of [kw ; qw]
        short8 bf[4];
#pragma unroll
        for (int ct = 0; ct < 4; ++ct) {
            const floatx4* wb = (ct < 2) ? kw4 : qw4;
            const int row = (ct & 1) * 16 + m;
            const floatx4 b0 = wb[row * 32 + kf4];
            const floatx4 b1 = wb[row * 32 + kf4 + 1];
            bf[ct] = pack8(b0, b1);
        }
#pragma unroll
        for (int rt = 0; rt < 4; ++rt) {
            const long long arow = blk_row + w * 64 + rt * 16 + m;
            const floatx4 a0 = __builtin_nontemporal_load(&f4[arow * 32 + kf4]);
            const floatx4 a1 = __builtin_nontemporal_load(&f4[arow * 32 + kf4 + 1]);
            const short8 af = pack8(a0, a1);
#pragma unroll
            for (int ct = 0; ct < 4; ++ct)
                acc[rt][ct] = __builtin_amdgcn_mfma_f32_16x16x32_bf16(af, bf[ct], acc[rt][ct], 0, 0, 0);
        }
    }

    // Epilogue: bias + bf16 store. C/D layout: col = lane&15, row = q*4+reg.
    float bias[4];
#pragma unroll
    for (int ct = 0; ct < 4; ++ct)
        bias[ct] = (ct < 2) ? kb[ct * 16 + m] : qb[(ct - 2) * 16 + m];

#pragma unroll
    for (int rt = 0; rt < 4; ++rt) {
#pragma unroll
        for (int reg = 0; reg < 4; ++reg) {
            const long long row = blk_row + w * 64 + rt * 16 + q * 4 + reg;
#pragma unroll
            for (int ct = 0; ct < 4; ++ct) {
                const float val = acc[rt][ct][reg] + bias[ct];
                if (ct < 2) tkb[row * DOUT + ct * 16 + m]       = f2bf(val);
                else        tqb[row * DOUT + (ct - 2) * 16 + m] = f2bf(val);
            }
        }
    }
}

// ---------------------------------------------------------------------------
// Kernel 2: gather + scaled dot on bf16 tables, cooperative-4.
// 4 lanes read one 64B row (4 x uint4), dot in-lane, 2-step shfl reduce.
// blockIdx%8 == batch: each batch's 4MB (tk+tq bf16) ~= one XCD's L2.
// idx loads / out stores are NONTEMPORAL so the streams don't evict the
// L2-resident tables.
// ---------------------------------------------------------------------------
__global__ __launch_bounds__(256) void gather_dot_kernel(
    const unsigned short* __restrict__ tkb, const unsigned short* __restrict__ tqb,
    const int* __restrict__ idx, float* __restrict__ out)
{
    const long long NK  = (long long)NNODES * KNBR;     // 262144 per batch
    const long long BNK = NK * BATCH;                   // 2097152 total

    const int b   = blockIdx.x & 7;
    const int blk = blockIdx.x >> 3;
    const int grp = threadIdx.x >> 2;   // 0..63: output within pass
    const int j   = threadIdx.x & 3;    // uint4 column within the 64B row

    const uintx4* tb_k = (const uintx4*)(tkb + (long long)b * NNODES * DOUT);
    const uintx4* tb_q = (const uintx4*)(tqb + (long long)b * NNODES * DOUT);

#pragma unroll
    for (int p = 0; p < 4; ++p) {
        const long long local = (long long)blk * 256 + p * 64 + grp;  // < NK
        const long long o     = (long long)b * NK + local;

        const int xi = __builtin_nontemporal_load(&idx[BNK + o]);        // channel 1
        const int yi = __builtin_nontemporal_load(&idx[2 * BNK + o]);    // channel 2

        const uintx4 x = tb_k[(long long)xi * 4 + j];
        const uintx4 y = tb_q[(long long)yi * 4 + j];
        float s = dot2bf(x.x, y.x) + dot2bf(x.y, y.y)
                + dot2bf(x.z, y.z) + dot2bf(x.w, y.w);
        s += __shfl_xor(s, 1);
        s += __shfl_xor(s, 2);
        if (j == 0)
            __builtin_nontemporal_store(s * 0.17677669529663687f, &out[o]);  // 32^-0.5
    }
}

// ---------------------------------------------------------------------------
extern "C" void kernel_launch(void* const* d_in, const int* in_sizes, int n_in,
                              void* d_out, int out_size, void* d_ws, size_t ws_size,
                              hipStream_t stream)
{
    const float* feats = (const float*)d_in[0];
    const float* kw    = (const float*)d_in[1];
    const float* kb    = (const float*)d_in[2];
    const float* qw    = (const float*)d_in[3];
    const float* qb    = (const float*)d_in[4];
    const int*   idx   = (const int*)d_in[5];
    float*       out   = (float*)d_out;

    // Workspace: two bf16 tables [B*N, 32] = 8 MB each
    unsigned short* tkb = (unsigned short*)d_ws;
    unsigned short* tqb = tkb + (long long)NROWS * DOUT;

    proj_kernel<<<NROWS / 256, 256, 0, stream>>>(feats, kw, kb, qw, qb, tkb, tqb);
    gather_dot_kernel<<<(int)((long long)BATCH * NNODES * KNBR / 256), 256, 0, stream>>>(
        tkb, tqb, idx, out);
}